// Round 2
// baseline (1244.477 us; speedup 1.0000x reference)
//
#include <hip/hip_runtime.h>
#include <hip/hip_bf16.h>

#define BN_EPS 1e-5f

typedef __attribute__((ext_vector_type(8))) short short8v;
typedef __attribute__((ext_vector_type(4))) float f32x4;
typedef __hip_bfloat16 bf16;

// ---------------------------------------------------------------- CSR build
__global__ void count_kernel(const int* __restrict__ dst, int* __restrict__ deg,
                             int E, int N) {
    int i = blockIdx.x * blockDim.x + threadIdx.x;
    if (i >= E) return;
    int d = dst[i];
    d = min(max(d, 0), N - 1);
    atomicAdd(&deg[d], 1);
}

__global__ __launch_bounds__(1024) void scan_kernel(const int* __restrict__ deg,
                                                    int* __restrict__ off,
                                                    int* __restrict__ cur, int N) {
    __shared__ int wsum[16];
    int t = threadIdx.x;
    int chunk = (N + 1023) / 1024;
    int lo = t * chunk, hi = min(N, lo + chunk);
    int s = 0;
    for (int i = lo; i < hi; ++i) s += deg[i];
    int lane = t & 63, w = t >> 6;
    int v = s;
#pragma unroll
    for (int d = 1; d < 64; d <<= 1) {
        int u = __shfl_up(v, d, 64);
        if (lane >= d) v += u;
    }
    if (lane == 63) wsum[w] = v;
    __syncthreads();
    if (w == 0 && lane < 16) {
        int xx = wsum[lane];
#pragma unroll
        for (int d = 1; d < 16; d <<= 1) {
            int u = __shfl_up(xx, d, 64);
            if (lane >= d) xx += u;
        }
        wsum[lane] = xx;
    }
    __syncthreads();
    int base = (w > 0 ? wsum[w - 1] : 0) + (v - s);  // exclusive prefix
    int run = base;
    for (int i = lo; i < hi; ++i) {
        off[i] = run; cur[i] = run; run += deg[i];
    }
    if (t == 1023) off[N] = run;
}

__global__ void fill_kernel(const int* __restrict__ dst, int* __restrict__ cur,
                            int* __restrict__ elist, int E, int N) {
    int i = blockIdx.x * blockDim.x + threadIdx.x;
    if (i >= E) return;
    int d = dst[i];
    d = min(max(d, 0), N - 1);
    int p = atomicAdd(&cur[d], 1);
    elist[p] = i;
}

// ---------------------------------------------------------- dtype converts
__global__ void conv_x_kernel(const float* __restrict__ in, bf16* __restrict__ out,
                              int n) {
    int i = (blockIdx.x * blockDim.x + threadIdx.x) * 4;
    if (i + 3 < n) {
        float4 v = *(const float4*)&in[i];
        out[i + 0] = __float2bfloat16(v.x);
        out[i + 1] = __float2bfloat16(v.y);
        out[i + 2] = __float2bfloat16(v.z);
        out[i + 3] = __float2bfloat16(v.w);
    } else {
        for (int j = i; j < n; ++j) out[j] = __float2bfloat16(in[j]);
    }
}

// transpose+convert all 6 MLP weights: wt[base + n*K + k] = w[k*N + n]
__global__ void conv_w_kernel(const float* __restrict__ w1a, const float* __restrict__ w1b,
                              const float* __restrict__ w2a, const float* __restrict__ w2b,
                              const float* __restrict__ w3a, const float* __restrict__ w3b,
                              bf16* __restrict__ wt) {
    int t = blockIdx.x * blockDim.x + threadIdx.x;
    const float* w; int K, N, base, r;
    if (t < 16384)       { w = w1a; K = 64;  N = 256; base = 0;      r = t; }
    else if (t < 81920)  { w = w1b; K = 256; N = 256; base = 16384;  r = t - 16384; }
    else if (t < 114688) { w = w2a; K = 256; N = 128; base = 81920;  r = t - 81920; }
    else if (t < 131072) { w = w2b; K = 128; N = 128; base = 114688; r = t - 114688; }
    else if (t < 139264) { w = w3a; K = 128; N = 64;  base = 131072; r = t - 131072; }
    else if (t < 143360) { w = w3b; K = 64;  N = 64;  base = 139264; r = t - 139264; }
    else return;
    int k = r % K, n = r / K;
    wt[base + r] = __float2bfloat16(w[(size_t)k * N + n]);
}

// ------------------------------------------------- fused message + aggregate
// t[n] = x[n] + sum_{e: dst(e)=n} relu(x[src(e)] + edge_attr[e] @ we + be)
// One wave per (node, 64-col chunk); edge loop unrolled x4 for MLP.
template <int D>
__global__ __launch_bounds__(256) void msg_kernel(
    const bf16* __restrict__ x, const float* __restrict__ ea,
    const int* __restrict__ src, const int* __restrict__ off,
    const int* __restrict__ elist, const float* __restrict__ we,
    const float* __restrict__ be, bf16* __restrict__ t, int N) {
    constexpr int NCH = D / 64;
    const int lane = threadIdx.x & 63;
    const int wid = blockIdx.x * 4 + (threadIdx.x >> 6);
    if (wid >= N * NCH) return;
    const int n = wid / NCH;
    const int c = wid % NCH;
    const int col = c * 64 + lane;

    float wreg[16];
#pragma unroll
    for (int k = 0; k < 16; ++k) wreg[k] = we[k * D + col];
    const float breg = be[col];

    float acc = 0.f;
    const int i0 = off[n], i1 = off[n + 1];
    int i = i0;
    for (; i + 4 <= i1; i += 4) {
        int ee[4], ss[4];
#pragma unroll
        for (int j = 0; j < 4; ++j) ee[j] = elist[i + j];
#pragma unroll
        for (int j = 0; j < 4; ++j) ss[j] = min(max(src[ee[j]], 0), N - 1);
        float er[4][16];
#pragma unroll
        for (int j = 0; j < 4; ++j)
#pragma unroll
            for (int q = 0; q < 4; ++q)
                *(float4*)&er[j][q * 4] = *(const float4*)&ea[(size_t)ee[j] * 16 + q * 4];
        float xv[4];
#pragma unroll
        for (int j = 0; j < 4; ++j)
            xv[j] = __bfloat162float(x[(size_t)ss[j] * D + col]);
#pragma unroll
        for (int j = 0; j < 4; ++j) {
            float m = breg;
#pragma unroll
            for (int k = 0; k < 16; ++k) m = fmaf(er[j][k], wreg[k], m);
            acc += fmaxf(m + xv[j], 0.f);
        }
    }
    for (; i < i1; ++i) {
        int e = elist[i];
        int s = min(max(src[e], 0), N - 1);
        float er1[16];
#pragma unroll
        for (int q = 0; q < 4; ++q)
            *(float4*)&er1[q * 4] = *(const float4*)&ea[(size_t)e * 16 + q * 4];
        float m = breg;
#pragma unroll
        for (int k = 0; k < 16; ++k) m = fmaf(er1[k], wreg[k], m);
        acc += fmaxf(m + __bfloat162float(x[(size_t)s * D + col]), 0.f);
    }

    t[(size_t)n * D + col] =
        __float2bfloat16(__bfloat162float(x[(size_t)n * D + col]) + acc);
}

// --------------------------------------------------------- bf16 MFMA GEMM
// C[m,n] = epi( sum_k A[m,k]*W[k,n] + bias[n] ),  W given transposed: Wt[n][k]
// mode 1: relu   mode 2: bn(relu(z))
// block = 256 thr = 4 waves; wave owns 32 rows (2 A frags); BM=128.
// mfma_f32_16x16x32_bf16 layouts: A row=lane&15, k=(lane>>4)*8+j;
// B k=(lane>>4)*8+j, col=lane&15; D col=lane&15, row=(lane>>4)*4+reg.
template <int NCOLS>
__global__ __launch_bounds__(256) void gemm_mfma(
    const bf16* __restrict__ A, const bf16* __restrict__ Wt,
    const float* __restrict__ bias, const float* __restrict__ bng,
    const float* __restrict__ bnb, const float* __restrict__ bnm,
    const float* __restrict__ bnv, bf16* __restrict__ C, int M, int K, int mode) {
    constexpr int NT = NCOLS / 16;
    const int lane = threadIdx.x & 63;
    const int w = threadIdx.x >> 6;
    const int mbase = blockIdx.x * 128 + w * 32;
    const int r16 = lane & 15;
    const int kg = lane >> 4;

    f32x4 acc[2][NT];
#pragma unroll
    for (int f = 0; f < 2; ++f)
#pragma unroll
        for (int nt = 0; nt < NT; ++nt) acc[f][nt] = (f32x4){0.f, 0.f, 0.f, 0.f};

    const short* Ap = (const short*)A;
    const short* Wp = (const short*)Wt;

    for (int k0 = 0; k0 < K; k0 += 32) {
        short8v a0 = *(const short8v*)&Ap[(size_t)(mbase + r16) * K + k0 + kg * 8];
        short8v a1 = *(const short8v*)&Ap[(size_t)(mbase + 16 + r16) * K + k0 + kg * 8];
#pragma unroll
        for (int nt = 0; nt < NT; ++nt) {
            short8v b = *(const short8v*)&Wp[(size_t)(nt * 16 + r16) * K + k0 + kg * 8];
            acc[0][nt] = __builtin_amdgcn_mfma_f32_16x16x32_bf16(a0, b, acc[0][nt], 0, 0, 0);
            acc[1][nt] = __builtin_amdgcn_mfma_f32_16x16x32_bf16(a1, b, acc[1][nt], 0, 0, 0);
        }
    }

#pragma unroll
    for (int nt = 0; nt < NT; ++nt) {
        int col = nt * 16 + r16;
        float bs = bias[col];
        float sc = 1.f, sh = 0.f;
        if (mode == 2) {
            sc = rsqrtf(bnv[col] + BN_EPS) * bng[col];
            sh = bnb[col] - bnm[col] * sc;
        }
#pragma unroll
        for (int f = 0; f < 2; ++f) {
#pragma unroll
            for (int rg = 0; rg < 4; ++rg) {
                int row = mbase + f * 16 + kg * 4 + rg;
                if (row >= M) continue;
                float z = acc[f][nt][rg] + bs;
                z = fmaxf(z, 0.f);
                if (mode == 2) z = z * sc + sh;
                C[(size_t)row * NCOLS + col] = __float2bfloat16(z);
            }
        }
    }
}

// ----------------------------------------------------------------- pooling
__global__ __launch_bounds__(256) void pool_kernel(const bf16* __restrict__ h,
                                                   const int* __restrict__ batch,
                                                   float* __restrict__ pooled, int N) {
    const int lane = threadIdx.x & 63;
    const int wid = blockIdx.x * 4 + (threadIdx.x >> 6);
    if (wid >= N) return;
    int g = batch[wid];
    g = min(max(g, 0), 127);
    atomicAdd(&pooled[g * 64 + lane], __bfloat162float(h[(size_t)wid * 64 + lane]));
}

// -------------------------------------------------------------------- head
__global__ __launch_bounds__(128) void head_kernel(
    const float* __restrict__ pooled, const float* __restrict__ w1,
    const float* __restrict__ b1, const float* __restrict__ w2,
    const float* __restrict__ b2, float* __restrict__ out) {
    const int g = threadIdx.x;
    float p[64];
#pragma unroll
    for (int i = 0; i < 64; ++i) p[i] = pooled[g * 64 + i];
    float o = b2[0];
#pragma unroll
    for (int j = 0; j < 16; ++j) {
        float hsum = b1[j];
#pragma unroll
        for (int i = 0; i < 64; ++i) hsum = fmaf(p[i], w1[i * 16 + j], hsum);
        o = fmaf(fmaxf(hsum, 0.f), w2[j], o);
    }
    out[g] = o;
}

// ------------------------------------------------------------------ launch
extern "C" void kernel_launch(void* const* d_in, const int* in_sizes, int n_in,
                              void* d_out, int out_size, void* d_ws,
                              size_t ws_size, hipStream_t stream) {
    const float* x     = (const float*)d_in[0];
    const float* ea    = (const float*)d_in[1];
    const int*   ei    = (const int*)d_in[2];
    const int*   batch = (const int*)d_in[3];
    const float* we1 = (const float*)d_in[4];
    const float* be1 = (const float*)d_in[5];
    const float* w1a = (const float*)d_in[6];
    const float* b1a = (const float*)d_in[7];
    const float* w1b = (const float*)d_in[8];
    const float* b1b = (const float*)d_in[9];
    const float* bn1g = (const float*)d_in[10];
    const float* bn1b = (const float*)d_in[11];
    const float* bn1m = (const float*)d_in[12];
    const float* bn1v = (const float*)d_in[13];
    const float* we2 = (const float*)d_in[14];
    const float* be2 = (const float*)d_in[15];
    const float* w2a = (const float*)d_in[16];
    const float* b2a = (const float*)d_in[17];
    const float* w2b = (const float*)d_in[18];
    const float* b2b = (const float*)d_in[19];
    const float* bn2g = (const float*)d_in[20];
    const float* bn2b = (const float*)d_in[21];
    const float* bn2m = (const float*)d_in[22];
    const float* bn2v = (const float*)d_in[23];
    const float* we3 = (const float*)d_in[24];
    const float* be3 = (const float*)d_in[25];
    const float* w3a = (const float*)d_in[26];
    const float* b3a = (const float*)d_in[27];
    const float* w3b = (const float*)d_in[28];
    const float* b3b = (const float*)d_in[29];
    const float* bn3g = (const float*)d_in[30];
    const float* bn3b = (const float*)d_in[31];
    const float* bn3m = (const float*)d_in[32];
    const float* bn3v = (const float*)d_in[33];
    const float* fc1w = (const float*)d_in[34];
    const float* fc1b = (const float*)d_in[35];
    const float* fc2w = (const float*)d_in[36];
    const float* fc2b = (const float*)d_in[37];

    const int N = in_sizes[0] / 64;
    const int E = in_sizes[1] / 16;
    const int M_pad = ((N + 127) / 128) * 128;
    const int* src = ei;
    const int* dst = ei + E;

    char* wsp = (char*)d_ws;
    auto alloc = [&](size_t bytes) -> void* {
        void* p = (void*)wsp;
        wsp += (bytes + 255) & ~(size_t)255;
        return p;
    };
    int* deg     = (int*)alloc((size_t)N * 4);
    int* off     = (int*)alloc((size_t)(N + 1) * 4);
    int* cur     = (int*)alloc((size_t)N * 4);
    int* elist   = (int*)alloc((size_t)E * 4);
    bf16* xb     = (bf16*)alloc((size_t)N * 64 * 2);
    bf16* tb     = (bf16*)alloc((size_t)M_pad * 256 * 2);
    bf16* ub     = (bf16*)alloc((size_t)M_pad * 256 * 2);
    bf16* hb     = (bf16*)alloc((size_t)M_pad * 256 * 2);
    bf16* wt     = (bf16*)alloc((size_t)143360 * 2);
    float* pooled = (float*)alloc(128 * 64 * 4);

    bf16* wt1a = wt + 0;
    bf16* wt1b = wt + 16384;
    bf16* wt2a = wt + 81920;
    bf16* wt2b = wt + 114688;
    bf16* wt3a = wt + 131072;
    bf16* wt3b = wt + 139264;

    hipMemsetAsync(deg, 0, (size_t)N * 4, stream);
    hipMemsetAsync(pooled, 0, 128 * 64 * 4, stream);

    // conversions (independent of CSR)
    conv_x_kernel<<<(N * 64 / 4 + 255) / 256, 256, 0, stream>>>(x, xb, N * 64);
    conv_w_kernel<<<(143360 + 255) / 256, 256, 0, stream>>>(w1a, w1b, w2a, w2b,
                                                            w3a, w3b, wt);

    int eb = (E + 255) / 256;
    count_kernel<<<eb, 256, 0, stream>>>(dst, deg, E, N);
    scan_kernel<<<1, 1024, 0, stream>>>(deg, off, cur, N);
    fill_kernel<<<eb, 256, 0, stream>>>(dst, cur, elist, E, N);

    const int gblk = M_pad / 128;

    // ---- layer 1 (64 -> 256)
    msg_kernel<64><<<(N * 1 + 3) / 4, 256, 0, stream>>>(xb, ea, src, off, elist,
                                                        we1, be1, tb, N);
    gemm_mfma<256><<<gblk, 256, 0, stream>>>(tb, wt1a, b1a, nullptr, nullptr, nullptr,
                                             nullptr, ub, N, 64, 1);
    gemm_mfma<256><<<gblk, 256, 0, stream>>>(ub, wt1b, b1b, bn1g, bn1b, bn1m, bn1v,
                                             hb, N, 256, 2);
    // ---- layer 2 (256 -> 128)
    msg_kernel<256><<<(N * 4 + 3) / 4, 256, 0, stream>>>(hb, ea, src, off, elist,
                                                         we2, be2, tb, N);
    gemm_mfma<128><<<gblk, 256, 0, stream>>>(tb, wt2a, b2a, nullptr, nullptr, nullptr,
                                             nullptr, ub, N, 256, 1);
    gemm_mfma<128><<<gblk, 256, 0, stream>>>(ub, wt2b, b2b, bn2g, bn2b, bn2m, bn2v,
                                             hb, N, 128, 2);
    // ---- layer 3 (128 -> 64)
    msg_kernel<128><<<(N * 2 + 3) / 4, 256, 0, stream>>>(hb, ea, src, off, elist,
                                                         we3, be3, tb, N);
    gemm_mfma<64><<<gblk, 256, 0, stream>>>(tb, wt3a, b3a, nullptr, nullptr, nullptr,
                                            nullptr, ub, N, 128, 1);
    gemm_mfma<64><<<gblk, 256, 0, stream>>>(ub, wt3b, b3b, bn3g, bn3b, bn3m, bn3v,
                                            hb, N, 64, 2);

    // ---- pool + head
    pool_kernel<<<(N + 3) / 4, 256, 0, stream>>>(hb, batch, pooled, N);
    head_kernel<<<1, 128, 0, stream>>>(pooled, fc1w, fc1b, fc2w, fc2b, (float*)d_out);
}